// Round 13
// baseline (206.092 us; speedup 1.0000x reference)
//
#include <hip/hip_runtime.h>
#include <stdint.h>

#define N_NODES 50000
#define N_EDGES 800000
#define IN_DIM  128
#define HID_DIM 64
#define OUT_DIM 64

#define NPB     256                         // partition blocks (= grid of k_build)
#define EPB     (N_EDGES / NPB)             // 3125 edges per block (exact)
#define BSH     9                           // bucket shift: 512 nodes/bucket
#define NB      ((N_NODES + 511) >> BSH)    // 98 buckets
#define CSR_CAP 12288                       // LDS-staged edges per bucket (48KB)

// ---------------------------------------------------------------------------
// bf16 helpers (RNE pack, bit-shift unpack; accumulate in fp32)
// ---------------------------------------------------------------------------
__device__ __forceinline__ uint32_t f2bf(float f) {
    uint32_t u = __float_as_uint(f);
    return (u + 0x7FFFu + ((u >> 16) & 1u)) >> 16;
}
__device__ __forceinline__ uint32_t pack2bf(float a, float b) {
    return f2bf(a) | (f2bf(b) << 16);
}
__device__ __forceinline__ float bflo(uint32_t v) { return __uint_as_float(v << 16); }
__device__ __forceinline__ float bfhi(uint32_t v) { return __uint_as_float(v & 0xFFFF0000u); }

// ---------------------------------------------------------------------------
// k_zc: zero the grid-barrier counters (one-shot barriers, re-zeroed per call)
// ---------------------------------------------------------------------------
__global__ void k_zc(int* __restrict__ ctr) {
    if (threadIdx.x < 4) ctr[threadIdx.x] = 0;
}

// ---------------------------------------------------------------------------
// grid barrier: all NPB blocks co-resident by capacity (53KB LDS -> >=1/CU,
// 256 blocks on 256 CUs).  Release fence + device-scope atomic arrive; spin
// with s_sleep; acquire fence after.
// ---------------------------------------------------------------------------
__device__ __forceinline__ void gridbar(int* ctr) {
    __syncthreads();
    if (threadIdx.x == 0) {
        __threadfence();                       // release: publish block's writes
        atomicAdd(ctr, 1);
        while (atomicAdd(ctr, 0) < NPB) __builtin_amdgcn_s_sleep(4);
    }
    __syncthreads();
    __threadfence();                           // acquire: see remote writes
}

// ---------------------------------------------------------------------------
// k_build: fused CSR construction (hist -> scan -> partition -> per-bucket
// CSR+dinv), one kernel, 3 grid barriers.  smem reused across phases.
// ---------------------------------------------------------------------------
__global__ __launch_bounds__(256) void k_build(const int* __restrict__ ei,
                                               int* __restrict__ histT,
                                               int* __restrict__ bucketstart,
                                               int* __restrict__ brec,
                                               int* __restrict__ rowstart,
                                               float* __restrict__ dinv,
                                               unsigned short* __restrict__ edata,
                                               int* __restrict__ ctr) {
    __shared__ int smem[CSR_CAP + 512 + 512 + 4];     // 53.3KB, phase-shared
    const int blk = blockIdx.x, tid = threadIdx.x;

    // ---- phase 1: per-(block,bucket) histogram ----
    {
        int* hist = smem;
        if (tid < NB) hist[tid] = 0;
        __syncthreads();
        const int e0 = blk * EPB;
        for (int e = e0 + tid; e < e0 + EPB; e += 256)
            atomicAdd(&hist[ei[N_EDGES + e] >> BSH], 1);
        __syncthreads();
        if (tid < NB) histT[tid * NPB + blk] = hist[tid];
    }
    gridbar(ctr + 0);

    // ---- phase 2: exclusive scan of histT (block 0 only) ----
    if (blk == 0) {
        const int CH = (NB * NPB) / 256;      // 98 contiguous elements/thread
        const int base = tid * CH;
        int s = 0;
        for (int i = 0; i < CH; ++i) s += histT[base + i];
        int wid = tid >> 6, lane = tid & 63;
        int incl = s;
        for (int o = 1; o < 64; o <<= 1) {
            int v = __shfl_up(incl, o, 64);
            if (lane >= o) incl += v;
        }
        int* wt = smem;
        if (lane == 63) wt[wid] = incl;
        __syncthreads();
        int woff = 0;
        for (int w = 0; w < wid; ++w) woff += wt[w];
        int excl = woff + incl - s;
        for (int i = 0; i < CH; ++i) {
            int v = histT[base + i];
            histT[base + i] = excl;
            excl += v;
        }
        __syncthreads();
        if (tid < NB) bucketstart[tid] = histT[tid * NPB];
        if (tid == 0) bucketstart[NB] = N_EDGES;
    }
    gridbar(ctr + 1);

    // ---- phase 3: partition edges into bucket chunks ----
    {
        int* cursor = smem;
        if (tid < NB) cursor[tid] = histT[tid * NPB + blk];
        __syncthreads();
        const int e0 = blk * EPB;
        for (int e = e0 + tid; e < e0 + EPB; e += 256) {
            int s = ei[e];
            int d = ei[N_EDGES + e];
            int b = d >> BSH;
            int pos = atomicAdd(&cursor[b], 1);
            brec[pos] = s | ((d & 511) << 16);
        }
    }
    gridbar(ctr + 2);

    // ---- phase 4: per-bucket CSR finalize (blocks 0..NB-1) ----
    if (blk >= NB) return;
    {
        int* sbuf   = smem;
        int* deg    = smem + CSR_CAP;
        int* segoff = deg + 512;
        int* wt     = segoff + 512;
        const int b = blk;
        const int lo = b << BSH;
        const int cstart = bucketstart[b];
        const int cend   = bucketstart[b + 1];
        const int cnt    = cend - cstart;
        const bool fit   = (cnt <= CSR_CAP);

        deg[tid] = 0;
        deg[tid + 256] = 0;
        if (fit) {
            for (int j = tid; j < cnt; j += 256) sbuf[j] = brec[cstart + j];
        }
        __syncthreads();

        if (fit) {
            for (int j = tid; j < cnt; j += 256) atomicAdd(&deg[sbuf[j] >> 16], 1);
        } else {
            for (int j = cstart + tid; j < cend; j += 256) atomicAdd(&deg[brec[j] >> 16], 1);
        }
        __syncthreads();

        const int i0 = tid << 1;
        const int d0 = deg[i0], d1 = deg[i0 + 1];
        const int s = d0 + d1;
        int wid = tid >> 6, lane = tid & 63;
        int incl = s;
        for (int o = 1; o < 64; o <<= 1) {
            int v = __shfl_up(incl, o, 64);
            if (lane >= o) incl += v;
        }
        if (lane == 63) wt[wid] = incl;
        __syncthreads();
        int woff = 0;
        for (int w = 0; w < wid; ++w) woff += wt[w];
        const int excl = woff + incl - s;

        segoff[i0]     = excl;
        segoff[i0 + 1] = excl + d0;

        if (lo + i0 < N_NODES) {
            rowstart[lo + i0] = cstart + excl;
            dinv[lo + i0] = rsqrtf((float)d0 + 1.0f);
        }
        if (lo + i0 + 1 < N_NODES) {
            rowstart[lo + i0 + 1] = cstart + excl + d0;
            dinv[lo + i0 + 1] = rsqrtf((float)d1 + 1.0f);
        }
        if (b == NB - 1 && tid == 0) rowstart[N_NODES] = cend;
        __syncthreads();

        if (fit) {
            for (int j = tid; j < cnt; j += 256) {
                int rec = sbuf[j];
                int pos = cstart + atomicAdd(&segoff[rec >> 16], 1);
                edata[pos] = (unsigned short)(rec & 0xFFFF);
            }
        } else {
            for (int j = cstart + tid; j < cend; j += 256) {
                int rec = brec[j];
                int pos = cstart + atomicAdd(&segoff[rec >> 16], 1);
                edata[pos] = (unsigned short)(rec & 0xFFFF);
            }
        }
    }
}

// ---------------------------------------------------------------------------
// k_gemm3: HSB[n,64] (bf16) = (X[n,K] @ W[K,64]) * dinv[row].
// ---------------------------------------------------------------------------
__device__ __forceinline__ void fma4(float4& acc, const float4& xv,
                                     const float4& w0, const float4& w1,
                                     const float4& w2, const float4& w3) {
    acc.x += xv.x * w0.x + xv.y * w1.x + xv.z * w2.x + xv.w * w3.x;
    acc.y += xv.x * w0.y + xv.y * w1.y + xv.z * w2.y + xv.w * w3.y;
    acc.z += xv.x * w0.z + xv.y * w1.z + xv.z * w2.z + xv.w * w3.z;
    acc.w += xv.x * w0.w + xv.y * w1.w + xv.z * w2.w + xv.w * w3.w;
}

__device__ __forceinline__ uint2 packbf4(const float4& a, float s) {
    return make_uint2(pack2bf(a.x * s, a.y * s), pack2bf(a.z * s, a.w * s));
}

template <int K>
__global__ __launch_bounds__(256) void k_gemm3(const float* __restrict__ X,
                                               const float* __restrict__ W,
                                               const float* __restrict__ dinv,
                                               uint32_t* __restrict__ HSB, int n) {
    constexpr int QK = K / 4;
    __shared__ float4 Ws[K * 16];
    const int tid = threadIdx.x;
    const int row0 = blockIdx.x * 64;

    for (int f = tid; f < K * 16; f += 256) Ws[f] = ((const float4*)W)[f];
    __syncthreads();

    const int c4 = tid & 15;
    const int r0 = row0 + ((tid >> 4) << 2);
    const float4* Xq = (const float4*)X;

    float4 a0 = make_float4(0.f, 0.f, 0.f, 0.f);
    float4 a1 = a0, a2 = a0, a3 = a0;

    if (r0 + 3 < n) {
        const float4* xp0 = Xq + (size_t)r0 * QK;
        const float4* xp1 = xp0 + QK;
        const float4* xp2 = xp1 + QK;
        const float4* xp3 = xp2 + QK;
#pragma unroll 4
        for (int k4 = 0; k4 < QK; ++k4) {
            const float4 x0 = xp0[k4];
            const float4 x1 = xp1[k4];
            const float4 x2 = xp2[k4];
            const float4 x3 = xp3[k4];
            const float4 w0 = Ws[(k4 * 4 + 0) * 16 + c4];
            const float4 w1 = Ws[(k4 * 4 + 1) * 16 + c4];
            const float4 w2 = Ws[(k4 * 4 + 2) * 16 + c4];
            const float4 w3 = Ws[(k4 * 4 + 3) * 16 + c4];
            fma4(a0, x0, w0, w1, w2, w3);
            fma4(a1, x1, w0, w1, w2, w3);
            fma4(a2, x2, w0, w1, w2, w3);
            fma4(a3, x3, w0, w1, w2, w3);
        }
        const float4 dv = ((const float4*)dinv)[r0 >> 2];
        ((uint2*)HSB)[((size_t)(r0 + 0) * 32 + c4 * 2) >> 1] = packbf4(a0, dv.x);
        ((uint2*)HSB)[((size_t)(r0 + 1) * 32 + c4 * 2) >> 1] = packbf4(a1, dv.y);
        ((uint2*)HSB)[((size_t)(r0 + 2) * 32 + c4 * 2) >> 1] = packbf4(a2, dv.z);
        ((uint2*)HSB)[((size_t)(r0 + 3) * 32 + c4 * 2) >> 1] = packbf4(a3, dv.w);
    } else {
        const float4 z = make_float4(0.f, 0.f, 0.f, 0.f);
        for (int k4 = 0; k4 < QK; ++k4) {
            const float4 x0 = (r0 + 0 < n) ? Xq[(size_t)(r0 + 0) * QK + k4] : z;
            const float4 x1 = (r0 + 1 < n) ? Xq[(size_t)(r0 + 1) * QK + k4] : z;
            const float4 x2 = (r0 + 2 < n) ? Xq[(size_t)(r0 + 2) * QK + k4] : z;
            const float4 x3 = (r0 + 3 < n) ? Xq[(size_t)(r0 + 3) * QK + k4] : z;
            const float4 w0 = Ws[(k4 * 4 + 0) * 16 + c4];
            const float4 w1 = Ws[(k4 * 4 + 1) * 16 + c4];
            const float4 w2 = Ws[(k4 * 4 + 2) * 16 + c4];
            const float4 w3 = Ws[(k4 * 4 + 3) * 16 + c4];
            fma4(a0, x0, w0, w1, w2, w3);
            fma4(a1, x1, w0, w1, w2, w3);
            fma4(a2, x2, w0, w1, w2, w3);
            fma4(a3, x3, w0, w1, w2, w3);
        }
        if (r0 + 0 < n) ((uint2*)HSB)[((size_t)(r0 + 0) * 32 + c4 * 2) >> 1] = packbf4(a0, dinv[r0 + 0]);
        if (r0 + 1 < n) ((uint2*)HSB)[((size_t)(r0 + 1) * 32 + c4 * 2) >> 1] = packbf4(a1, dinv[r0 + 1]);
        if (r0 + 2 < n) ((uint2*)HSB)[((size_t)(r0 + 2) * 32 + c4 * 2) >> 1] = packbf4(a2, dinv[r0 + 2]);
        if (r0 + 3 < n) ((uint2*)HSB)[((size_t)(r0 + 3) * 32 + c4 * 2) >> 1] = packbf4(a3, dinv[r0 + 3]);
    }
}

// ---------------------------------------------------------------------------
// k_gg2: FUSED gather1+ReLU (phase A, lean, unroll-8, results to LDS) and
// GEMM2 (phase B, W2 in LDS, 8 fp32 accs/thread, coalesced bf16 store).
// LDS-decoupled phases keep VGPR at gather level (round-9 lesson).
// ---------------------------------------------------------------------------
__global__ __launch_bounds__(256) void k_gg2(const int* __restrict__ rowstart,
                                             const unsigned short* __restrict__ edata,
                                             const uint32_t* __restrict__ hsb1,
                                             const float* __restrict__ dinv,
                                             const float* __restrict__ b1v,
                                             const float* __restrict__ W2,
                                             uint32_t* __restrict__ hsb2) {
    __shared__ float W2s[64 * 64];            // 16KB row-major [k][c]
    __shared__ float a1s[32][68];             // 8.7KB padded (16B-aligned rows)
    const int tid = threadIdx.x;

    // stage W2 (float4; in-flight during gather issue)
    for (int f = tid; f < 1024; f += 256)
        ((float4*)W2s)[f] = ((const float4*)W2)[f];

    // ---- phase A: gather + bias + relu -> a1s ----
    const int nl = tid >> 3;                  // local node 0..31
    const int lane = tid & 7;
    const int node = blockIdx.x * 32 + nl;
    if (node < N_NODES) {
        int start = rowstart[node];
        int end   = rowstart[node + 1];
        const uint4* hq = (const uint4*)hsb1;
        float a0 = 0.f, a1 = 0.f, a2 = 0.f, a3 = 0.f,
              a4 = 0.f, a5 = 0.f, a6 = 0.f, a7 = 0.f;
        int j = start;
        for (; j + 8 <= end; j += 8) {
            const int s0 = edata[j + 0];
            const int s1 = edata[j + 1];
            const int s2 = edata[j + 2];
            const int s3 = edata[j + 3];
            const int s4 = edata[j + 4];
            const int s5 = edata[j + 5];
            const int s6 = edata[j + 6];
            const int s7 = edata[j + 7];
            const uint4 v0 = hq[(size_t)s0 * 8 + lane];
            const uint4 v1 = hq[(size_t)s1 * 8 + lane];
            const uint4 v2 = hq[(size_t)s2 * 8 + lane];
            const uint4 v3 = hq[(size_t)s3 * 8 + lane];
            const uint4 v4 = hq[(size_t)s4 * 8 + lane];
            const uint4 v5 = hq[(size_t)s5 * 8 + lane];
            const uint4 v6 = hq[(size_t)s6 * 8 + lane];
            const uint4 v7 = hq[(size_t)s7 * 8 + lane];
            a0 += ((bflo(v0.x) + bflo(v1.x)) + (bflo(v2.x) + bflo(v3.x)))
                + ((bflo(v4.x) + bflo(v5.x)) + (bflo(v6.x) + bflo(v7.x)));
            a1 += ((bfhi(v0.x) + bfhi(v1.x)) + (bfhi(v2.x) + bfhi(v3.x)))
                + ((bfhi(v4.x) + bfhi(v5.x)) + (bfhi(v6.x) + bfhi(v7.x)));
            a2 += ((bflo(v0.y) + bflo(v1.y)) + (bflo(v2.y) + bflo(v3.y)))
                + ((bflo(v4.y) + bflo(v5.y)) + (bflo(v6.y) + bflo(v7.y)));
            a3 += ((bfhi(v0.y) + bfhi(v1.y)) + (bfhi(v2.y) + bfhi(v3.y)))
                + ((bfhi(v4.y) + bfhi(v5.y)) + (bfhi(v6.y) + bfhi(v7.y)));
            a4 += ((bflo(v0.z) + bflo(v1.z)) + (bflo(v2.z) + bflo(v3.z)))
                + ((bflo(v4.z) + bflo(v5.z)) + (bflo(v6.z) + bflo(v7.z)));
            a5 += ((bfhi(v0.z) + bfhi(v1.z)) + (bfhi(v2.z) + bfhi(v3.z)))
                + ((bfhi(v4.z) + bfhi(v5.z)) + (bfhi(v6.z) + bfhi(v7.z)));
            a6 += ((bflo(v0.w) + bflo(v1.w)) + (bflo(v2.w) + bflo(v3.w)))
                + ((bflo(v4.w) + bflo(v5.w)) + (bflo(v6.w) + bflo(v7.w)));
            a7 += ((bfhi(v0.w) + bfhi(v1.w)) + (bfhi(v2.w) + bfhi(v3.w)))
                + ((bfhi(v4.w) + bfhi(v5.w)) + (bfhi(v6.w) + bfhi(v7.w)));
        }
        for (; j + 4 <= end; j += 4) {
            const int s0 = edata[j + 0];
            const int s1 = edata[j + 1];
            const int s2 = edata[j + 2];
            const int s3 = edata[j + 3];
            const uint4 v0 = hq[(size_t)s0 * 8 + lane];
            const uint4 v1 = hq[(size_t)s1 * 8 + lane];
            const uint4 v2 = hq[(size_t)s2 * 8 + lane];
            const uint4 v3 = hq[(size_t)s3 * 8 + lane];
            a0 += (bflo(v0.x) + bflo(v1.x)) + (bflo(v2.x) + bflo(v3.x));
            a1 += (bfhi(v0.x) + bfhi(v1.x)) + (bfhi(v2.x) + bfhi(v3.x));
            a2 += (bflo(v0.y) + bflo(v1.y)) + (bflo(v2.y) + bflo(v3.y));
            a3 += (bfhi(v0.y) + bfhi(v1.y)) + (bfhi(v2.y) + bfhi(v3.y));
            a4 += (bflo(v0.z) + bflo(v1.z)) + (bflo(v2.z) + bflo(v3.z));
            a5 += (bfhi(v0.z) + bfhi(v1.z)) + (bfhi(v2.z) + bfhi(v3.z));
            a6 += (bflo(v0.w) + bflo(v1.w)) + (bflo(v2.w) + bflo(v3.w));
            a7 += (bfhi(v0.w) + bfhi(v1.w)) + (bfhi(v2.w) + bfhi(v3.w));
        }
        for (; j < end; ++j) {
            const int s = edata[j];
            const uint4 v = hq[(size_t)s * 8 + lane];
            a0 += bflo(v.x); a1 += bfhi(v.x);
            a2 += bflo(v.y); a3 += bfhi(v.y);
            a4 += bflo(v.z); a5 += bfhi(v.z);
            a6 += bflo(v.w); a7 += bfhi(v.w);
        }
        {
            const uint4 v = hq[(size_t)node * 8 + lane];
            a0 += bflo(v.x); a1 += bfhi(v.x);
            a2 += bflo(v.y); a3 += bfhi(v.y);
            a4 += bflo(v.z); a5 += bfhi(v.z);
            a6 += bflo(v.w); a7 += bfhi(v.w);
        }
        const float di = dinv[node];
        const float4 b0 = *reinterpret_cast<const float4*>(&b1v[lane * 8]);
        const float4 b1 = *reinterpret_cast<const float4*>(&b1v[lane * 8 + 4]);
        float4 o0, o1;
        o0.x = fmaxf(a0 * di + b0.x, 0.f);
        o0.y = fmaxf(a1 * di + b0.y, 0.f);
        o0.z = fmaxf(a2 * di + b0.z, 0.f);
        o0.w = fmaxf(a3 * di + b0.w, 0.f);
        o1.x = fmaxf(a4 * di + b1.x, 0.f);
        o1.y = fmaxf(a5 * di + b1.y, 0.f);
        o1.z = fmaxf(a6 * di + b1.z, 0.f);
        o1.w = fmaxf(a7 * di + b1.w, 0.f);
        *reinterpret_cast<float4*>(&a1s[nl][lane * 8])     = o0;
        *reinterpret_cast<float4*>(&a1s[nl][lane * 8 + 4]) = o1;
    }

    __syncthreads();   // a1s + W2s ready

    // ---- phase B: hs2[node] = (a1s[node] @ W2) * dinv, packed bf16 ----
    const int gnode = blockIdx.x * 32 + (tid >> 3);
    if (gnode < N_NODES) {
        const int c8 = (tid & 7) * 8;
        const int nb = tid >> 3;
        float c0 = 0.f, c1 = 0.f, c2 = 0.f, c3 = 0.f,
              c4 = 0.f, c5 = 0.f, c6 = 0.f, c7 = 0.f;
#pragma unroll 8
        for (int k = 0; k < 64; ++k) {
            const float a = a1s[nb][k];
            const float4 w0 = *(const float4*)&W2s[k * 64 + c8];
            const float4 w1 = *(const float4*)&W2s[k * 64 + c8 + 4];
            c0 += a * w0.x; c1 += a * w0.y; c2 += a * w0.z; c3 += a * w0.w;
            c4 += a * w1.x; c5 += a * w1.y; c6 += a * w1.z; c7 += a * w1.w;
        }
        const float di = dinv[gnode];
        uint4 o;
        o.x = pack2bf(c0 * di, c1 * di);
        o.y = pack2bf(c2 * di, c3 * di);
        o.z = pack2bf(c4 * di, c5 * di);
        o.w = pack2bf(c6 * di, c7 * di);
        ((uint4*)hsb2)[(size_t)gnode * 8 + (tid & 7)] = o;
    }
}

// ---------------------------------------------------------------------------
// k_gather: full-row CSR gather, UNROLL-8 (layer-2 aggregate -> out).
// ---------------------------------------------------------------------------
template <bool RELU>
__global__ __launch_bounds__(256) void k_gather(const int* __restrict__ rowstart,
                                                const unsigned short* __restrict__ edata,
                                                const uint32_t* __restrict__ hsb,
                                                const float* __restrict__ dinv,
                                                const float* __restrict__ bias,
                                                float* __restrict__ out) {
    int node = blockIdx.x * 32 + (threadIdx.x >> 3);
    int lane = threadIdx.x & 7;
    if (node >= N_NODES) return;

    int start = rowstart[node];
    int end   = rowstart[node + 1];

    const uint4* hq = (const uint4*)hsb;
    float a0 = 0.f, a1 = 0.f, a2 = 0.f, a3 = 0.f,
          a4 = 0.f, a5 = 0.f, a6 = 0.f, a7 = 0.f;

    int j = start;
    for (; j + 8 <= end; j += 8) {
        const int s0 = edata[j + 0];
        const int s1 = edata[j + 1];
        const int s2 = edata[j + 2];
        const int s3 = edata[j + 3];
        const int s4 = edata[j + 4];
        const int s5 = edata[j + 5];
        const int s6 = edata[j + 6];
        const int s7 = edata[j + 7];
        const uint4 v0 = hq[(size_t)s0 * 8 + lane];
        const uint4 v1 = hq[(size_t)s1 * 8 + lane];
        const uint4 v2 = hq[(size_t)s2 * 8 + lane];
        const uint4 v3 = hq[(size_t)s3 * 8 + lane];
        const uint4 v4 = hq[(size_t)s4 * 8 + lane];
        const uint4 v5 = hq[(size_t)s5 * 8 + lane];
        const uint4 v6 = hq[(size_t)s6 * 8 + lane];
        const uint4 v7 = hq[(size_t)s7 * 8 + lane];
        a0 += ((bflo(v0.x) + bflo(v1.x)) + (bflo(v2.x) + bflo(v3.x)))
            + ((bflo(v4.x) + bflo(v5.x)) + (bflo(v6.x) + bflo(v7.x)));
        a1 += ((bfhi(v0.x) + bfhi(v1.x)) + (bfhi(v2.x) + bfhi(v3.x)))
            + ((bfhi(v4.x) + bfhi(v5.x)) + (bfhi(v6.x) + bfhi(v7.x)));
        a2 += ((bflo(v0.y) + bflo(v1.y)) + (bflo(v2.y) + bflo(v3.y)))
            + ((bflo(v4.y) + bflo(v5.y)) + (bflo(v6.y) + bflo(v7.y)));
        a3 += ((bfhi(v0.y) + bfhi(v1.y)) + (bfhi(v2.y) + bfhi(v3.y)))
            + ((bfhi(v4.y) + bfhi(v5.y)) + (bfhi(v6.y) + bfhi(v7.y)));
        a4 += ((bflo(v0.z) + bflo(v1.z)) + (bflo(v2.z) + bflo(v3.z)))
            + ((bflo(v4.z) + bflo(v5.z)) + (bflo(v6.z) + bflo(v7.z)));
        a5 += ((bfhi(v0.z) + bfhi(v1.z)) + (bfhi(v2.z) + bfhi(v3.z)))
            + ((bfhi(v4.z) + bfhi(v5.z)) + (bfhi(v6.z) + bfhi(v7.z)));
        a6 += ((bflo(v0.w) + bflo(v1.w)) + (bflo(v2.w) + bflo(v3.w)))
            + ((bflo(v4.w) + bflo(v5.w)) + (bflo(v6.w) + bflo(v7.w)));
        a7 += ((bfhi(v0.w) + bfhi(v1.w)) + (bfhi(v2.w) + bfhi(v3.w)))
            + ((bfhi(v4.w) + bfhi(v5.w)) + (bfhi(v6.w) + bfhi(v7.w)));
    }
    for (; j + 4 <= end; j += 4) {
        const int s0 = edata[j + 0];
        const int s1 = edata[j + 1];
        const int s2 = edata[j + 2];
        const int s3 = edata[j + 3];
        const uint4 v0 = hq[(size_t)s0 * 8 + lane];
        const uint4 v1 = hq[(size_t)s1 * 8 + lane];
        const uint4 v2 = hq[(size_t)s2 * 8 + lane];
        const uint4 v3 = hq[(size_t)s3 * 8 + lane];
        a0 += (bflo(v0.x) + bflo(v1.x)) + (bflo(v2.x) + bflo(v3.x));
        a1 += (bfhi(v0.x) + bfhi(v1.x)) + (bfhi(v2.x) + bfhi(v3.x));
        a2 += (bflo(v0.y) + bflo(v1.y)) + (bflo(v2.y) + bflo(v3.y));
        a3 += (bfhi(v0.y) + bfhi(v1.y)) + (bfhi(v2.y) + bfhi(v3.y));
        a4 += (bflo(v0.z) + bflo(v1.z)) + (bflo(v2.z) + bflo(v3.z));
        a5 += (bfhi(v0.z) + bfhi(v1.z)) + (bfhi(v2.z) + bfhi(v3.z));
        a6 += (bflo(v0.w) + bflo(v1.w)) + (bflo(v2.w) + bflo(v3.w));
        a7 += (bfhi(v0.w) + bfhi(v1.w)) + (bfhi(v2.w) + bfhi(v3.w));
    }
    for (; j < end; ++j) {
        const int s = edata[j];
        const uint4 v = hq[(size_t)s * 8 + lane];
        a0 += bflo(v.x); a1 += bfhi(v.x);
        a2 += bflo(v.y); a3 += bfhi(v.y);
        a4 += bflo(v.z); a5 += bfhi(v.z);
        a6 += bflo(v.w); a7 += bfhi(v.w);
    }
    {
        const uint4 v = hq[(size_t)node * 8 + lane];
        a0 += bflo(v.x); a1 += bfhi(v.x);
        a2 += bflo(v.y); a3 += bfhi(v.y);
        a4 += bflo(v.z); a5 += bfhi(v.z);
        a6 += bflo(v.w); a7 += bfhi(v.w);
    }

    const float di = dinv[node];
    const float4 b0 = *reinterpret_cast<const float4*>(&bias[lane * 8]);
    const float4 b1 = *reinterpret_cast<const float4*>(&bias[lane * 8 + 4]);
    float4 o0, o1;
    o0.x = a0 * di + b0.x;  o0.y = a1 * di + b0.y;
    o0.z = a2 * di + b0.z;  o0.w = a3 * di + b0.w;
    o1.x = a4 * di + b1.x;  o1.y = a5 * di + b1.y;
    o1.z = a6 * di + b1.z;  o1.w = a7 * di + b1.w;
    if (RELU) {
        o0.x = fmaxf(o0.x, 0.f); o0.y = fmaxf(o0.y, 0.f);
        o0.z = fmaxf(o0.z, 0.f); o0.w = fmaxf(o0.w, 0.f);
        o1.x = fmaxf(o1.x, 0.f); o1.y = fmaxf(o1.y, 0.f);
        o1.z = fmaxf(o1.z, 0.f); o1.w = fmaxf(o1.w, 0.f);
    }
    float4* op = (float4*)&out[(size_t)node * 64 + lane * 8];
    op[0] = o0;
    op[1] = o1;
}

extern "C" void kernel_launch(void* const* d_in, const int* in_sizes, int n_in,
                              void* d_out, int out_size, void* d_ws, size_t ws_size,
                              hipStream_t stream) {
    const float* x  = (const float*)d_in[0];
    const int*   ei = (const int*)d_in[1];    // [2, N_EDGES] int32
    const float* W1 = (const float*)d_in[2];
    const float* b1 = (const float*)d_in[3];
    const float* W2 = (const float*)d_in[4];
    const float* b2 = (const float*)d_in[5];
    float* out = (float*)d_out;

    // Workspace carve-up (16B-aligned chunks):
    //   ctr[4] | histT[25088] | bucketstart[100] | brec[E] | rowstart[N+4] |
    //   edata ushort[E] | dinv[N] | hsb1[N*32 u32] | hsb2[N*32 u32]
    int*            ctr         = (int*)d_ws;
    int*            histT       = ctr + 4;
    int*            bucketstart = histT + NB * NPB;             // 25088
    int*            brec        = bucketstart + (NB + 2);       // +100
    int*            rowstart    = brec + N_EDGES;
    unsigned short* edata       = (unsigned short*)(rowstart + (N_NODES + 4));
    float*          dinv        = (float*)(edata + N_EDGES);    // E even -> aligned
    uint32_t*       hsb1        = (uint32_t*)(dinv + N_NODES);  // bf16 [N][64]
    uint32_t*       hsb2        = hsb1 + (size_t)N_NODES * 32;  // bf16 [N][64]

    // --- CSR build: 2 dispatches (counter zero + fused build) ---
    k_zc<<<1, 64, 0, stream>>>(ctr);
    k_build<<<NPB, 256, 0, stream>>>(ei, histT, bucketstart, brec,
                                     rowstart, dinv, edata, ctr);

    // --- layer 1 GEMM ---
    k_gemm3<IN_DIM><<<(N_NODES + 63) / 64, 256, 0, stream>>>(x, W1, dinv, hsb1, N_NODES);
    // --- fused gather1 + ReLU + GEMM2 ---
    k_gg2<<<(N_NODES + 31) / 32, 256, 0, stream>>>(rowstart, edata, hsb1, dinv, b1, W2, hsb2);
    // --- layer 2 aggregate ---
    k_gather<false><<<(N_NODES + 31) / 32, 256, 0, stream>>>(rowstart, edata, hsb2, dinv, b2, out);
}

// Round 14
// 114.185 us; speedup vs baseline: 1.8049x; 1.8049x over previous
//
#include <hip/hip_runtime.h>
#include <stdint.h>

#define N_NODES 50000
#define N_EDGES 800000
#define IN_DIM  128
#define HID_DIM 64
#define OUT_DIM 64

#define NPB     256                         // partition blocks
#define EPB     (N_EDGES / NPB)             // 3125 edges per block (exact)
#define BSH     9                           // bucket shift: 512 nodes/bucket
#define NB      ((N_NODES + 511) >> BSH)    // 98 buckets
#define CSR_CAP 12288                       // LDS-staged edges per bucket (48KB)

// ---------------------------------------------------------------------------
// bf16 helpers (RNE pack, bit-shift unpack; accumulate in fp32)
// ---------------------------------------------------------------------------
__device__ __forceinline__ uint32_t f2bf(float f) {
    uint32_t u = __float_as_uint(f);
    return (u + 0x7FFFu + ((u >> 16) & 1u)) >> 16;
}
__device__ __forceinline__ uint32_t pack2bf(float a, float b) {
    return f2bf(a) | (f2bf(b) << 16);
}
__device__ __forceinline__ float bflo(uint32_t v) { return __uint_as_float(v << 16); }
__device__ __forceinline__ float bfhi(uint32_t v) { return __uint_as_float(v & 0xFFFF0000u); }

// ---------------------------------------------------------------------------
// k_bhist: per-(block,bucket) histogram of dst. histT[bkt*NPB + blk].
// ---------------------------------------------------------------------------
__global__ __launch_bounds__(256) void k_bhist(const int* __restrict__ ei,
                                               int* __restrict__ histT) {
    __shared__ int hist[NB];
    const int blk = blockIdx.x, tid = threadIdx.x;
    if (tid < NB) hist[tid] = 0;
    __syncthreads();
    const int e0 = blk * EPB;
    for (int e = e0 + tid; e < e0 + EPB; e += 256)
        atomicAdd(&hist[ei[N_EDGES + e] >> BSH], 1);
    __syncthreads();
    if (tid < NB) histT[tid * NPB + blk] = hist[tid];
}

// ---------------------------------------------------------------------------
// k_bscan: single-block exclusive scan (in place) of histT[NB*NPB] in
// bucket-major order; emits bucketstart[NB+1].
// ---------------------------------------------------------------------------
__global__ __launch_bounds__(256) void k_bscan(int* __restrict__ histT,
                                               int* __restrict__ bucketstart) {
    const int t = threadIdx.x;
    const int CH = (NB * NPB) / 256;        // 98 contiguous elements per thread
    const int base = t * CH;
    int s = 0;
#pragma unroll 7
    for (int i = 0; i < CH; ++i) s += histT[base + i];

    int wid = t >> 6, lane = t & 63;
    int incl = s;
    for (int o = 1; o < 64; o <<= 1) {
        int v = __shfl_up(incl, o, 64);
        if (lane >= o) incl += v;
    }
    __shared__ int wt[4];
    if (lane == 63) wt[wid] = incl;
    __syncthreads();
    int woff = 0;
    for (int w = 0; w < wid; ++w) woff += wt[w];
    int excl = woff + incl - s;

#pragma unroll 7
    for (int i = 0; i < CH; ++i) {
        int v = histT[base + i];
        histT[base + i] = excl;
        excl += v;
    }
    __syncthreads();
    if (t < NB) bucketstart[t] = histT[t * NPB];
    if (t == 0) bucketstart[NB] = N_EDGES;
}

// ---------------------------------------------------------------------------
// k_part: re-stream edges; write rec = src | dlo<<16 into this block's
// reserved contiguous chunk of each bucket (coalesced-ish, XCD-friendly).
// ---------------------------------------------------------------------------
__global__ __launch_bounds__(256) void k_part(const int* __restrict__ ei,
                                              const int* __restrict__ histT,
                                              int* __restrict__ brec) {
    __shared__ int cursor[NB];
    const int blk = blockIdx.x, tid = threadIdx.x;
    if (tid < NB) cursor[tid] = histT[tid * NPB + blk];
    __syncthreads();
    const int e0 = blk * EPB;
    for (int e = e0 + tid; e < e0 + EPB; e += 256) {
        int s = ei[e];
        int d = ei[N_EDGES + e];
        int b = d >> BSH;
        int pos = atomicAdd(&cursor[b], 1);
        brec[pos] = s | ((d & 511) << 16);
    }
}

// ---------------------------------------------------------------------------
// k_csr: one block per bucket (512 nodes).  Stages the bucket's brec chunk
// in LDS once (fallback to global if oversized), counts per-node deg,
// block-scans, emits rowstart & dinv, scatters edata (src ushort).
// ---------------------------------------------------------------------------
__global__ __launch_bounds__(256) void k_csr(const int* __restrict__ brec,
                                             const int* __restrict__ bucketstart,
                                             int* __restrict__ rowstart,
                                             float* __restrict__ dinv,
                                             unsigned short* __restrict__ edata) {
    __shared__ int deg[512];
    __shared__ int segoff[512];
    __shared__ int wt[4];
    __shared__ int sbuf[CSR_CAP];
    const int b = blockIdx.x, tid = threadIdx.x;
    const int lo = b << BSH;
    const int cstart = bucketstart[b];
    const int cend   = bucketstart[b + 1];
    const int cnt    = cend - cstart;
    const bool fit   = (cnt <= CSR_CAP);

    deg[tid] = 0;
    deg[tid + 256] = 0;
    if (fit) {
        for (int j = tid; j < cnt; j += 256) sbuf[j] = brec[cstart + j];
    }
    __syncthreads();

    // pass 1: per-node degree
    if (fit) {
        for (int j = tid; j < cnt; j += 256) atomicAdd(&deg[sbuf[j] >> 16], 1);
    } else {
        for (int j = cstart + tid; j < cend; j += 256) atomicAdd(&deg[brec[j] >> 16], 1);
    }
    __syncthreads();

    const int i0 = tid << 1;
    const int d0 = deg[i0], d1 = deg[i0 + 1];
    const int s = d0 + d1;
    int wid = tid >> 6, lane = tid & 63;
    int incl = s;
    for (int o = 1; o < 64; o <<= 1) {
        int v = __shfl_up(incl, o, 64);
        if (lane >= o) incl += v;
    }
    if (lane == 63) wt[wid] = incl;
    __syncthreads();
    int woff = 0;
    for (int w = 0; w < wid; ++w) woff += wt[w];
    const int excl = woff + incl - s;

    segoff[i0]     = excl;
    segoff[i0 + 1] = excl + d0;

    if (lo + i0 < N_NODES) {
        rowstart[lo + i0] = cstart + excl;
        dinv[lo + i0] = rsqrtf((float)d0 + 1.0f);
    }
    if (lo + i0 + 1 < N_NODES) {
        rowstart[lo + i0 + 1] = cstart + excl + d0;
        dinv[lo + i0 + 1] = rsqrtf((float)d1 + 1.0f);
    }
    if (b == NB - 1 && tid == 0) rowstart[N_NODES] = cend;
    __syncthreads();

    // pass 2: scatter into final CSR slots
    if (fit) {
        for (int j = tid; j < cnt; j += 256) {
            int rec = sbuf[j];
            int pos = cstart + atomicAdd(&segoff[rec >> 16], 1);
            edata[pos] = (unsigned short)(rec & 0xFFFF);
        }
    } else {
        for (int j = cstart + tid; j < cend; j += 256) {
            int rec = brec[j];
            int pos = cstart + atomicAdd(&segoff[rec >> 16], 1);
            edata[pos] = (unsigned short)(rec & 0xFFFF);
        }
    }
}

// ---------------------------------------------------------------------------
// k_gemm3: HSB[n,64] (bf16) = (X[n,K] @ W[K,64]) * dinv[row].
// ---------------------------------------------------------------------------
__device__ __forceinline__ void fma4(float4& acc, const float4& xv,
                                     const float4& w0, const float4& w1,
                                     const float4& w2, const float4& w3) {
    acc.x += xv.x * w0.x + xv.y * w1.x + xv.z * w2.x + xv.w * w3.x;
    acc.y += xv.x * w0.y + xv.y * w1.y + xv.z * w2.y + xv.w * w3.y;
    acc.z += xv.x * w0.z + xv.y * w1.z + xv.z * w2.z + xv.w * w3.z;
    acc.w += xv.x * w0.w + xv.y * w1.w + xv.z * w2.w + xv.w * w3.w;
}

__device__ __forceinline__ uint2 packbf4(const float4& a, float s) {
    return make_uint2(pack2bf(a.x * s, a.y * s), pack2bf(a.z * s, a.w * s));
}

template <int K>
__global__ __launch_bounds__(256) void k_gemm3(const float* __restrict__ X,
                                               const float* __restrict__ W,
                                               const float* __restrict__ dinv,
                                               uint32_t* __restrict__ HSB, int n) {
    constexpr int QK = K / 4;
    __shared__ float4 Ws[K * 16];
    const int tid = threadIdx.x;
    const int row0 = blockIdx.x * 64;

    for (int f = tid; f < K * 16; f += 256) Ws[f] = ((const float4*)W)[f];
    __syncthreads();

    const int c4 = tid & 15;
    const int r0 = row0 + ((tid >> 4) << 2);
    const float4* Xq = (const float4*)X;

    float4 a0 = make_float4(0.f, 0.f, 0.f, 0.f);
    float4 a1 = a0, a2 = a0, a3 = a0;

    if (r0 + 3 < n) {
        const float4* xp0 = Xq + (size_t)r0 * QK;
        const float4* xp1 = xp0 + QK;
        const float4* xp2 = xp1 + QK;
        const float4* xp3 = xp2 + QK;
#pragma unroll 4
        for (int k4 = 0; k4 < QK; ++k4) {
            const float4 x0 = xp0[k4];
            const float4 x1 = xp1[k4];
            const float4 x2 = xp2[k4];
            const float4 x3 = xp3[k4];
            const float4 w0 = Ws[(k4 * 4 + 0) * 16 + c4];
            const float4 w1 = Ws[(k4 * 4 + 1) * 16 + c4];
            const float4 w2 = Ws[(k4 * 4 + 2) * 16 + c4];
            const float4 w3 = Ws[(k4 * 4 + 3) * 16 + c4];
            fma4(a0, x0, w0, w1, w2, w3);
            fma4(a1, x1, w0, w1, w2, w3);
            fma4(a2, x2, w0, w1, w2, w3);
            fma4(a3, x3, w0, w1, w2, w3);
        }
        const float4 dv = ((const float4*)dinv)[r0 >> 2];
        ((uint2*)HSB)[((size_t)(r0 + 0) * 32 + c4 * 2) >> 1] = packbf4(a0, dv.x);
        ((uint2*)HSB)[((size_t)(r0 + 1) * 32 + c4 * 2) >> 1] = packbf4(a1, dv.y);
        ((uint2*)HSB)[((size_t)(r0 + 2) * 32 + c4 * 2) >> 1] = packbf4(a2, dv.z);
        ((uint2*)HSB)[((size_t)(r0 + 3) * 32 + c4 * 2) >> 1] = packbf4(a3, dv.w);
    } else {
        const float4 z = make_float4(0.f, 0.f, 0.f, 0.f);
        for (int k4 = 0; k4 < QK; ++k4) {
            const float4 x0 = (r0 + 0 < n) ? Xq[(size_t)(r0 + 0) * QK + k4] : z;
            const float4 x1 = (r0 + 1 < n) ? Xq[(size_t)(r0 + 1) * QK + k4] : z;
            const float4 x2 = (r0 + 2 < n) ? Xq[(size_t)(r0 + 2) * QK + k4] : z;
            const float4 x3 = (r0 + 3 < n) ? Xq[(size_t)(r0 + 3) * QK + k4] : z;
            const float4 w0 = Ws[(k4 * 4 + 0) * 16 + c4];
            const float4 w1 = Ws[(k4 * 4 + 1) * 16 + c4];
            const float4 w2 = Ws[(k4 * 4 + 2) * 16 + c4];
            const float4 w3 = Ws[(k4 * 4 + 3) * 16 + c4];
            fma4(a0, x0, w0, w1, w2, w3);
            fma4(a1, x1, w0, w1, w2, w3);
            fma4(a2, x2, w0, w1, w2, w3);
            fma4(a3, x3, w0, w1, w2, w3);
        }
        if (r0 + 0 < n) ((uint2*)HSB)[((size_t)(r0 + 0) * 32 + c4 * 2) >> 1] = packbf4(a0, dinv[r0 + 0]);
        if (r0 + 1 < n) ((uint2*)HSB)[((size_t)(r0 + 1) * 32 + c4 * 2) >> 1] = packbf4(a1, dinv[r0 + 1]);
        if (r0 + 2 < n) ((uint2*)HSB)[((size_t)(r0 + 2) * 32 + c4 * 2) >> 1] = packbf4(a2, dinv[r0 + 2]);
        if (r0 + 3 < n) ((uint2*)HSB)[((size_t)(r0 + 3) * 32 + c4 * 2) >> 1] = packbf4(a3, dinv[r0 + 3]);
    }
}

// ---------------------------------------------------------------------------
// k_gg2: FUSED gather1+ReLU (phase A, lean, unroll-8, results to LDS) and
// GEMM2 (phase B, W2 in LDS, 8 fp32 accs/thread, coalesced bf16 store).
// LDS-decoupled phases keep VGPR at gather level (round-9 lesson).
// ---------------------------------------------------------------------------
__global__ __launch_bounds__(256) void k_gg2(const int* __restrict__ rowstart,
                                             const unsigned short* __restrict__ edata,
                                             const uint32_t* __restrict__ hsb1,
                                             const float* __restrict__ dinv,
                                             const float* __restrict__ b1v,
                                             const float* __restrict__ W2,
                                             uint32_t* __restrict__ hsb2) {
    __shared__ float W2s[64 * 64];            // 16KB row-major [k][c]
    __shared__ float a1s[32][68];             // 8.7KB padded (16B-aligned rows)
    const int tid = threadIdx.x;

    // stage W2 (float4; in-flight during gather issue)
    for (int f = tid; f < 1024; f += 256)
        ((float4*)W2s)[f] = ((const float4*)W2)[f];

    // ---- phase A: gather + bias + relu -> a1s ----
    const int nl = tid >> 3;                  // local node 0..31
    const int lane = tid & 7;
    const int node = blockIdx.x * 32 + nl;
    if (node < N_NODES) {
        int start = rowstart[node];
        int end   = rowstart[node + 1];
        const uint4* hq = (const uint4*)hsb1;
        float a0 = 0.f, a1 = 0.f, a2 = 0.f, a3 = 0.f,
              a4 = 0.f, a5 = 0.f, a6 = 0.f, a7 = 0.f;
        int j = start;
        for (; j + 8 <= end; j += 8) {
            const int s0 = edata[j + 0];
            const int s1 = edata[j + 1];
            const int s2 = edata[j + 2];
            const int s3 = edata[j + 3];
            const int s4 = edata[j + 4];
            const int s5 = edata[j + 5];
            const int s6 = edata[j + 6];
            const int s7 = edata[j + 7];
            const uint4 v0 = hq[(size_t)s0 * 8 + lane];
            const uint4 v1 = hq[(size_t)s1 * 8 + lane];
            const uint4 v2 = hq[(size_t)s2 * 8 + lane];
            const uint4 v3 = hq[(size_t)s3 * 8 + lane];
            const uint4 v4 = hq[(size_t)s4 * 8 + lane];
            const uint4 v5 = hq[(size_t)s5 * 8 + lane];
            const uint4 v6 = hq[(size_t)s6 * 8 + lane];
            const uint4 v7 = hq[(size_t)s7 * 8 + lane];
            a0 += ((bflo(v0.x) + bflo(v1.x)) + (bflo(v2.x) + bflo(v3.x)))
                + ((bflo(v4.x) + bflo(v5.x)) + (bflo(v6.x) + bflo(v7.x)));
            a1 += ((bfhi(v0.x) + bfhi(v1.x)) + (bfhi(v2.x) + bfhi(v3.x)))
                + ((bfhi(v4.x) + bfhi(v5.x)) + (bfhi(v6.x) + bfhi(v7.x)));
            a2 += ((bflo(v0.y) + bflo(v1.y)) + (bflo(v2.y) + bflo(v3.y)))
                + ((bflo(v4.y) + bflo(v5.y)) + (bflo(v6.y) + bflo(v7.y)));
            a3 += ((bfhi(v0.y) + bfhi(v1.y)) + (bfhi(v2.y) + bfhi(v3.y)))
                + ((bfhi(v4.y) + bfhi(v5.y)) + (bfhi(v6.y) + bfhi(v7.y)));
            a4 += ((bflo(v0.z) + bflo(v1.z)) + (bflo(v2.z) + bflo(v3.z)))
                + ((bflo(v4.z) + bflo(v5.z)) + (bflo(v6.z) + bflo(v7.z)));
            a5 += ((bfhi(v0.z) + bfhi(v1.z)) + (bfhi(v2.z) + bfhi(v3.z)))
                + ((bfhi(v4.z) + bfhi(v5.z)) + (bfhi(v6.z) + bfhi(v7.z)));
            a6 += ((bflo(v0.w) + bflo(v1.w)) + (bflo(v2.w) + bflo(v3.w)))
                + ((bflo(v4.w) + bflo(v5.w)) + (bflo(v6.w) + bflo(v7.w)));
            a7 += ((bfhi(v0.w) + bfhi(v1.w)) + (bfhi(v2.w) + bfhi(v3.w)))
                + ((bfhi(v4.w) + bfhi(v5.w)) + (bfhi(v6.w) + bfhi(v7.w)));
        }
        for (; j + 4 <= end; j += 4) {
            const int s0 = edata[j + 0];
            const int s1 = edata[j + 1];
            const int s2 = edata[j + 2];
            const int s3 = edata[j + 3];
            const uint4 v0 = hq[(size_t)s0 * 8 + lane];
            const uint4 v1 = hq[(size_t)s1 * 8 + lane];
            const uint4 v2 = hq[(size_t)s2 * 8 + lane];
            const uint4 v3 = hq[(size_t)s3 * 8 + lane];
            a0 += (bflo(v0.x) + bflo(v1.x)) + (bflo(v2.x) + bflo(v3.x));
            a1 += (bfhi(v0.x) + bfhi(v1.x)) + (bfhi(v2.x) + bfhi(v3.x));
            a2 += (bflo(v0.y) + bflo(v1.y)) + (bflo(v2.y) + bflo(v3.y));
            a3 += (bfhi(v0.y) + bfhi(v1.y)) + (bfhi(v2.y) + bfhi(v3.y));
            a4 += (bflo(v0.z) + bflo(v1.z)) + (bflo(v2.z) + bflo(v3.z));
            a5 += (bfhi(v0.z) + bfhi(v1.z)) + (bfhi(v2.z) + bfhi(v3.z));
            a6 += (bflo(v0.w) + bflo(v1.w)) + (bflo(v2.w) + bflo(v3.w));
            a7 += (bfhi(v0.w) + bfhi(v1.w)) + (bfhi(v2.w) + bfhi(v3.w));
        }
        for (; j < end; ++j) {
            const int s = edata[j];
            const uint4 v = hq[(size_t)s * 8 + lane];
            a0 += bflo(v.x); a1 += bfhi(v.x);
            a2 += bflo(v.y); a3 += bfhi(v.y);
            a4 += bflo(v.z); a5 += bfhi(v.z);
            a6 += bflo(v.w); a7 += bfhi(v.w);
        }
        {
            const uint4 v = hq[(size_t)node * 8 + lane];
            a0 += bflo(v.x); a1 += bfhi(v.x);
            a2 += bflo(v.y); a3 += bfhi(v.y);
            a4 += bflo(v.z); a5 += bfhi(v.z);
            a6 += bflo(v.w); a7 += bfhi(v.w);
        }
        const float di = dinv[node];
        const float4 b0 = *reinterpret_cast<const float4*>(&b1v[lane * 8]);
        const float4 b1 = *reinterpret_cast<const float4*>(&b1v[lane * 8 + 4]);
        float4 o0, o1;
        o0.x = fmaxf(a0 * di + b0.x, 0.f);
        o0.y = fmaxf(a1 * di + b0.y, 0.f);
        o0.z = fmaxf(a2 * di + b0.z, 0.f);
        o0.w = fmaxf(a3 * di + b0.w, 0.f);
        o1.x = fmaxf(a4 * di + b1.x, 0.f);
        o1.y = fmaxf(a5 * di + b1.y, 0.f);
        o1.z = fmaxf(a6 * di + b1.z, 0.f);
        o1.w = fmaxf(a7 * di + b1.w, 0.f);
        *reinterpret_cast<float4*>(&a1s[nl][lane * 8])     = o0;
        *reinterpret_cast<float4*>(&a1s[nl][lane * 8 + 4]) = o1;
    }

    __syncthreads();   // a1s + W2s ready

    // ---- phase B: hs2[node] = (a1s[node] @ W2) * dinv, packed bf16 ----
    const int gnode = blockIdx.x * 32 + (tid >> 3);
    if (gnode < N_NODES) {
        const int c8 = (tid & 7) * 8;
        const int nb = tid >> 3;
        float c0 = 0.f, c1 = 0.f, c2 = 0.f, c3 = 0.f,
              c4 = 0.f, c5 = 0.f, c6 = 0.f, c7 = 0.f;
#pragma unroll 8
        for (int k = 0; k < 64; ++k) {
            const float a = a1s[nb][k];
            const float4 w0 = *(const float4*)&W2s[k * 64 + c8];
            const float4 w1 = *(const float4*)&W2s[k * 64 + c8 + 4];
            c0 += a * w0.x; c1 += a * w0.y; c2 += a * w0.z; c3 += a * w0.w;
            c4 += a * w1.x; c5 += a * w1.y; c6 += a * w1.z; c7 += a * w1.w;
        }
        const float di = dinv[gnode];
        uint4 o;
        o.x = pack2bf(c0 * di, c1 * di);
        o.y = pack2bf(c2 * di, c3 * di);
        o.z = pack2bf(c4 * di, c5 * di);
        o.w = pack2bf(c6 * di, c7 * di);
        ((uint4*)hsb2)[(size_t)gnode * 8 + (tid & 7)] = o;
    }
}

// ---------------------------------------------------------------------------
// k_gather: full-row CSR gather, UNROLL-8 (layer-2 aggregate -> out).
// ---------------------------------------------------------------------------
template <bool RELU>
__global__ __launch_bounds__(256) void k_gather(const int* __restrict__ rowstart,
                                                const unsigned short* __restrict__ edata,
                                                const uint32_t* __restrict__ hsb,
                                                const float* __restrict__ dinv,
                                                const float* __restrict__ bias,
                                                float* __restrict__ out) {
    int node = blockIdx.x * 32 + (threadIdx.x >> 3);
    int lane = threadIdx.x & 7;
    if (node >= N_NODES) return;

    int start = rowstart[node];
    int end   = rowstart[node + 1];

    const uint4* hq = (const uint4*)hsb;
    float a0 = 0.f, a1 = 0.f, a2 = 0.f, a3 = 0.f,
          a4 = 0.f, a5 = 0.f, a6 = 0.f, a7 = 0.f;

    int j = start;
    for (; j + 8 <= end; j += 8) {
        const int s0 = edata[j + 0];
        const int s1 = edata[j + 1];
        const int s2 = edata[j + 2];
        const int s3 = edata[j + 3];
        const int s4 = edata[j + 4];
        const int s5 = edata[j + 5];
        const int s6 = edata[j + 6];
        const int s7 = edata[j + 7];
        const uint4 v0 = hq[(size_t)s0 * 8 + lane];
        const uint4 v1 = hq[(size_t)s1 * 8 + lane];
        const uint4 v2 = hq[(size_t)s2 * 8 + lane];
        const uint4 v3 = hq[(size_t)s3 * 8 + lane];
        const uint4 v4 = hq[(size_t)s4 * 8 + lane];
        const uint4 v5 = hq[(size_t)s5 * 8 + lane];
        const uint4 v6 = hq[(size_t)s6 * 8 + lane];
        const uint4 v7 = hq[(size_t)s7 * 8 + lane];
        a0 += ((bflo(v0.x) + bflo(v1.x)) + (bflo(v2.x) + bflo(v3.x)))
            + ((bflo(v4.x) + bflo(v5.x)) + (bflo(v6.x) + bflo(v7.x)));
        a1 += ((bfhi(v0.x) + bfhi(v1.x)) + (bfhi(v2.x) + bfhi(v3.x)))
            + ((bfhi(v4.x) + bfhi(v5.x)) + (bfhi(v6.x) + bfhi(v7.x)));
        a2 += ((bflo(v0.y) + bflo(v1.y)) + (bflo(v2.y) + bflo(v3.y)))
            + ((bflo(v4.y) + bflo(v5.y)) + (bflo(v6.y) + bflo(v7.y)));
        a3 += ((bfhi(v0.y) + bfhi(v1.y)) + (bfhi(v2.y) + bfhi(v3.y)))
            + ((bfhi(v4.y) + bfhi(v5.y)) + (bfhi(v6.y) + bfhi(v7.y)));
        a4 += ((bflo(v0.z) + bflo(v1.z)) + (bflo(v2.z) + bflo(v3.z)))
            + ((bflo(v4.z) + bflo(v5.z)) + (bflo(v6.z) + bflo(v7.z)));
        a5 += ((bfhi(v0.z) + bfhi(v1.z)) + (bfhi(v2.z) + bfhi(v3.z)))
            + ((bfhi(v4.z) + bfhi(v5.z)) + (bfhi(v6.z) + bfhi(v7.z)));
        a6 += ((bflo(v0.w) + bflo(v1.w)) + (bflo(v2.w) + bflo(v3.w)))
            + ((bflo(v4.w) + bflo(v5.w)) + (bflo(v6.w) + bflo(v7.w)));
        a7 += ((bfhi(v0.w) + bfhi(v1.w)) + (bfhi(v2.w) + bfhi(v3.w)))
            + ((bfhi(v4.w) + bfhi(v5.w)) + (bfhi(v6.w) + bfhi(v7.w)));
    }
    for (; j + 4 <= end; j += 4) {
        const int s0 = edata[j + 0];
        const int s1 = edata[j + 1];
        const int s2 = edata[j + 2];
        const int s3 = edata[j + 3];
        const uint4 v0 = hq[(size_t)s0 * 8 + lane];
        const uint4 v1 = hq[(size_t)s1 * 8 + lane];
        const uint4 v2 = hq[(size_t)s2 * 8 + lane];
        const uint4 v3 = hq[(size_t)s3 * 8 + lane];
        a0 += (bflo(v0.x) + bflo(v1.x)) + (bflo(v2.x) + bflo(v3.x));
        a1 += (bfhi(v0.x) + bfhi(v1.x)) + (bfhi(v2.x) + bfhi(v3.x));
        a2 += (bflo(v0.y) + bflo(v1.y)) + (bflo(v2.y) + bflo(v3.y));
        a3 += (bfhi(v0.y) + bfhi(v1.y)) + (bfhi(v2.y) + bfhi(v3.y));
        a4 += (bflo(v0.z) + bflo(v1.z)) + (bflo(v2.z) + bflo(v3.z));
        a5 += (bfhi(v0.z) + bfhi(v1.z)) + (bfhi(v2.z) + bfhi(v3.z));
        a6 += (bflo(v0.w) + bflo(v1.w)) + (bflo(v2.w) + bflo(v3.w));
        a7 += (bfhi(v0.w) + bfhi(v1.w)) + (bfhi(v2.w) + bfhi(v3.w));
    }
    for (; j < end; ++j) {
        const int s = edata[j];
        const uint4 v = hq[(size_t)s * 8 + lane];
        a0 += bflo(v.x); a1 += bfhi(v.x);
        a2 += bflo(v.y); a3 += bfhi(v.y);
        a4 += bflo(v.z); a5 += bfhi(v.z);
        a6 += bflo(v.w); a7 += bfhi(v.w);
    }
    {
        const uint4 v = hq[(size_t)node * 8 + lane];
        a0 += bflo(v.x); a1 += bfhi(v.x);
        a2 += bflo(v.y); a3 += bfhi(v.y);
        a4 += bflo(v.z); a5 += bfhi(v.z);
        a6 += bflo(v.w); a7 += bfhi(v.w);
    }

    const float di = dinv[node];
    const float4 b0 = *reinterpret_cast<const float4*>(&bias[lane * 8]);
    const float4 b1 = *reinterpret_cast<const float4*>(&bias[lane * 8 + 4]);
    float4 o0, o1;
    o0.x = a0 * di + b0.x;  o0.y = a1 * di + b0.y;
    o0.z = a2 * di + b0.z;  o0.w = a3 * di + b0.w;
    o1.x = a4 * di + b1.x;  o1.y = a5 * di + b1.y;
    o1.z = a6 * di + b1.z;  o1.w = a7 * di + b1.w;
    if (RELU) {
        o0.x = fmaxf(o0.x, 0.f); o0.y = fmaxf(o0.y, 0.f);
        o0.z = fmaxf(o0.z, 0.f); o0.w = fmaxf(o0.w, 0.f);
        o1.x = fmaxf(o1.x, 0.f); o1.y = fmaxf(o1.y, 0.f);
        o1.z = fmaxf(o1.z, 0.f); o1.w = fmaxf(o1.w, 0.f);
    }
    float4* op = (float4*)&out[(size_t)node * 64 + lane * 8];
    op[0] = o0;
    op[1] = o1;
}

extern "C" void kernel_launch(void* const* d_in, const int* in_sizes, int n_in,
                              void* d_out, int out_size, void* d_ws, size_t ws_size,
                              hipStream_t stream) {
    const float* x  = (const float*)d_in[0];
    const int*   ei = (const int*)d_in[1];    // [2, N_EDGES] int32
    const float* W1 = (const float*)d_in[2];
    const float* b1 = (const float*)d_in[3];
    const float* W2 = (const float*)d_in[4];
    const float* b2 = (const float*)d_in[5];
    float* out = (float*)d_out;

    // Workspace carve-up (16B-aligned chunks):
    //   histT[25088] | bucketstart[100] | brec[E] | rowstart[N+4] |
    //   edata ushort[E] | dinv[N] | hsb1[N*32 u32] | hsb2[N*32 u32]
    int*            histT       = (int*)d_ws;
    int*            bucketstart = histT + NB * NPB;             // 25088
    int*            brec        = bucketstart + (NB + 2);       // +100
    int*            rowstart    = brec + N_EDGES;
    unsigned short* edata       = (unsigned short*)(rowstart + (N_NODES + 4));
    float*          dinv        = (float*)(edata + N_EDGES);    // E even -> aligned
    uint32_t*       hsb1        = (uint32_t*)(dinv + N_NODES);  // bf16 [N][64]
    uint32_t*       hsb2        = hsb1 + (size_t)N_NODES * 32;  // bf16 [N][64]

    // --- CSR build (counting-sort partition, 4 kernels — no grid barrier) ---
    k_bhist<<<NPB, 256, 0, stream>>>(ei, histT);
    k_bscan<<<1, 256, 0, stream>>>(histT, bucketstart);
    k_part<<<NPB, 256, 0, stream>>>(ei, histT, brec);
    k_csr<<<NB, 256, 0, stream>>>(brec, bucketstart, rowstart, dinv, edata);

    // --- layer 1 GEMM ---
    k_gemm3<IN_DIM><<<(N_NODES + 63) / 64, 256, 0, stream>>>(x, W1, dinv, hsb1, N_NODES);
    // --- fused gather1 + ReLU + GEMM2 ---
    k_gg2<<<(N_NODES + 31) / 32, 256, 0, stream>>>(rowstart, edata, hsb1, dinv, b1, W2, hsb2);
    // --- layer 2 aggregate ---
    k_gather<false><<<(N_NODES + 31) / 32, 256, 0, stream>>>(rowstart, edata, hsb2, dinv, b2, out);
}

// Round 15
// 108.250 us; speedup vs baseline: 1.9038x; 1.0548x over previous
//
#include <hip/hip_runtime.h>
#include <stdint.h>

#define N_NODES 50000
#define N_EDGES 800000
#define IN_DIM  128
#define HID_DIM 64
#define OUT_DIM 64

#define NPB     256                         // partition blocks
#define EPB     (N_EDGES / NPB)             // 3125 edges per block (exact)
#define BSH     9                           // bucket shift: 512 nodes/bucket
#define NB      ((N_NODES + 511) >> BSH)    // 98 buckets
#define BCAP    10240                       // per-bucket capacity (mean 8192 + 22 sigma)

// ---------------------------------------------------------------------------
// bf16 helpers (RNE pack, bit-shift unpack; accumulate in fp32)
// ---------------------------------------------------------------------------
__device__ __forceinline__ uint32_t f2bf(float f) {
    uint32_t u = __float_as_uint(f);
    return (u + 0x7FFFu + ((u >> 16) & 1u)) >> 16;
}
__device__ __forceinline__ uint32_t pack2bf(float a, float b) {
    return f2bf(a) | (f2bf(b) << 16);
}
__device__ __forceinline__ float bflo(uint32_t v) { return __uint_as_float(v << 16); }
__device__ __forceinline__ float bfhi(uint32_t v) { return __uint_as_float(v & 0xFFFF0000u); }

// ---------------------------------------------------------------------------
// k_zc: zero the per-bucket reservation cursors (replay-safe)
// ---------------------------------------------------------------------------
__global__ void k_zc(int* __restrict__ bucketcnt) {
    if (threadIdx.x < 128) bucketcnt[threadIdx.x] = 0;
}

// ---------------------------------------------------------------------------
// k_part2: FUSED histogram + chunk reservation + partition.
// Per block: LDS hist of its 3125 dsts; ONE atomicAdd per (block,bucket) to
// reserve a contiguous chunk in bucket b's fixed region [b*BCAP, (b+1)*BCAP);
// re-stream edges scattering rec = src | dlo<<16 via LDS cursors.
// ---------------------------------------------------------------------------
__global__ __launch_bounds__(256) void k_part2(const int* __restrict__ ei,
                                               int* __restrict__ bucketcnt,
                                               int* __restrict__ brec) {
    __shared__ int hist[NB];
    __shared__ int cursor[NB];
    const int blk = blockIdx.x, tid = threadIdx.x;
    if (tid < NB) hist[tid] = 0;
    __syncthreads();
    const int e0 = blk * EPB;
    for (int e = e0 + tid; e < e0 + EPB; e += 256)
        atomicAdd(&hist[ei[N_EDGES + e] >> BSH], 1);
    __syncthreads();
    if (tid < NB) {
        int c = hist[tid];
        int base = (c > 0) ? atomicAdd(&bucketcnt[tid], c) : 0;
        cursor[tid] = tid * BCAP + base;
    }
    __syncthreads();
    for (int e = e0 + tid; e < e0 + EPB; e += 256) {
        int s = ei[e];
        int d = ei[N_EDGES + e];
        int b = d >> BSH;
        int pos = atomicAdd(&cursor[b], 1);
        if (pos < (b + 1) * BCAP)                       // overflow guard
            brec[pos] = s | ((d & 511) << 16);
    }
}

// ---------------------------------------------------------------------------
// k_csr2: one block per bucket (512 nodes).  Stages the bucket's records in
// LDS, counts per-node deg, block-scans, emits rowstart (absolute, padded
// layout) + rowcnt + dinv, scatters edata (src ushort) into bucket region.
// ---------------------------------------------------------------------------
__global__ __launch_bounds__(256) void k_csr2(const int* __restrict__ brec,
                                              const int* __restrict__ bucketcnt,
                                              int* __restrict__ rowstart,
                                              int* __restrict__ rowcnt,
                                              float* __restrict__ dinv,
                                              unsigned short* __restrict__ edata) {
    __shared__ int sbuf[BCAP];               // 40KB
    __shared__ int deg[512];
    __shared__ int segoff[512];
    __shared__ int wt[4];
    const int b = blockIdx.x, tid = threadIdx.x;
    const int lo = b << BSH;
    const int cbase = b * BCAP;
    int cnt = bucketcnt[b];
    if (cnt > BCAP) cnt = BCAP;

    deg[tid] = 0;
    deg[tid + 256] = 0;
    for (int j = tid; j < cnt; j += 256) sbuf[j] = brec[cbase + j];
    __syncthreads();

    // pass 1: per-node degree
    for (int j = tid; j < cnt; j += 256) atomicAdd(&deg[sbuf[j] >> 16], 1);
    __syncthreads();

    // block exclusive scan over 512 degs (2 per thread)
    const int i0 = tid << 1;
    const int d0 = deg[i0], d1 = deg[i0 + 1];
    const int s = d0 + d1;
    int wid = tid >> 6, lane = tid & 63;
    int incl = s;
    for (int o = 1; o < 64; o <<= 1) {
        int v = __shfl_up(incl, o, 64);
        if (lane >= o) incl += v;
    }
    if (lane == 63) wt[wid] = incl;
    __syncthreads();
    int woff = 0;
    for (int w = 0; w < wid; ++w) woff += wt[w];
    const int excl = woff + incl - s;

    segoff[i0]     = excl;
    segoff[i0 + 1] = excl + d0;

    if (lo + i0 < N_NODES) {
        rowstart[lo + i0] = cbase + excl;
        rowcnt[lo + i0]   = d0;
        dinv[lo + i0] = rsqrtf((float)d0 + 1.0f);
    }
    if (lo + i0 + 1 < N_NODES) {
        rowstart[lo + i0 + 1] = cbase + excl + d0;
        rowcnt[lo + i0 + 1]   = d1;
        dinv[lo + i0 + 1] = rsqrtf((float)d1 + 1.0f);
    }
    __syncthreads();

    // pass 2: scatter into final CSR slots (bucket-local region)
    for (int j = tid; j < cnt; j += 256) {
        int rec = sbuf[j];
        int pos = cbase + atomicAdd(&segoff[rec >> 16], 1);
        edata[pos] = (unsigned short)(rec & 0xFFFF);
    }
}

// ---------------------------------------------------------------------------
// k_gemm3: HSB[n,64] (bf16) = (X[n,K] @ W[K,64]) * dinv[row].
// ---------------------------------------------------------------------------
__device__ __forceinline__ void fma4(float4& acc, const float4& xv,
                                     const float4& w0, const float4& w1,
                                     const float4& w2, const float4& w3) {
    acc.x += xv.x * w0.x + xv.y * w1.x + xv.z * w2.x + xv.w * w3.x;
    acc.y += xv.x * w0.y + xv.y * w1.y + xv.z * w2.y + xv.w * w3.y;
    acc.z += xv.x * w0.z + xv.y * w1.z + xv.z * w2.z + xv.w * w3.z;
    acc.w += xv.x * w0.w + xv.y * w1.w + xv.z * w2.w + xv.w * w3.w;
}

__device__ __forceinline__ uint2 packbf4(const float4& a, float s) {
    return make_uint2(pack2bf(a.x * s, a.y * s), pack2bf(a.z * s, a.w * s));
}

template <int K>
__global__ __launch_bounds__(256) void k_gemm3(const float* __restrict__ X,
                                               const float* __restrict__ W,
                                               const float* __restrict__ dinv,
                                               uint32_t* __restrict__ HSB, int n) {
    constexpr int QK = K / 4;
    __shared__ float4 Ws[K * 16];
    const int tid = threadIdx.x;
    const int row0 = blockIdx.x * 64;

    for (int f = tid; f < K * 16; f += 256) Ws[f] = ((const float4*)W)[f];
    __syncthreads();

    const int c4 = tid & 15;
    const int r0 = row0 + ((tid >> 4) << 2);
    const float4* Xq = (const float4*)X;

    float4 a0 = make_float4(0.f, 0.f, 0.f, 0.f);
    float4 a1 = a0, a2 = a0, a3 = a0;

    if (r0 + 3 < n) {
        const float4* xp0 = Xq + (size_t)r0 * QK;
        const float4* xp1 = xp0 + QK;
        const float4* xp2 = xp1 + QK;
        const float4* xp3 = xp2 + QK;
#pragma unroll 4
        for (int k4 = 0; k4 < QK; ++k4) {
            const float4 x0 = xp0[k4];
            const float4 x1 = xp1[k4];
            const float4 x2 = xp2[k4];
            const float4 x3 = xp3[k4];
            const float4 w0 = Ws[(k4 * 4 + 0) * 16 + c4];
            const float4 w1 = Ws[(k4 * 4 + 1) * 16 + c4];
            const float4 w2 = Ws[(k4 * 4 + 2) * 16 + c4];
            const float4 w3 = Ws[(k4 * 4 + 3) * 16 + c4];
            fma4(a0, x0, w0, w1, w2, w3);
            fma4(a1, x1, w0, w1, w2, w3);
            fma4(a2, x2, w0, w1, w2, w3);
            fma4(a3, x3, w0, w1, w2, w3);
        }
        const float4 dv = ((const float4*)dinv)[r0 >> 2];
        ((uint2*)HSB)[((size_t)(r0 + 0) * 32 + c4 * 2) >> 1] = packbf4(a0, dv.x);
        ((uint2*)HSB)[((size_t)(r0 + 1) * 32 + c4 * 2) >> 1] = packbf4(a1, dv.y);
        ((uint2*)HSB)[((size_t)(r0 + 2) * 32 + c4 * 2) >> 1] = packbf4(a2, dv.z);
        ((uint2*)HSB)[((size_t)(r0 + 3) * 32 + c4 * 2) >> 1] = packbf4(a3, dv.w);
    } else {
        const float4 z = make_float4(0.f, 0.f, 0.f, 0.f);
        for (int k4 = 0; k4 < QK; ++k4) {
            const float4 x0 = (r0 + 0 < n) ? Xq[(size_t)(r0 + 0) * QK + k4] : z;
            const float4 x1 = (r0 + 1 < n) ? Xq[(size_t)(r0 + 1) * QK + k4] : z;
            const float4 x2 = (r0 + 2 < n) ? Xq[(size_t)(r0 + 2) * QK + k4] : z;
            const float4 x3 = (r0 + 3 < n) ? Xq[(size_t)(r0 + 3) * QK + k4] : z;
            const float4 w0 = Ws[(k4 * 4 + 0) * 16 + c4];
            const float4 w1 = Ws[(k4 * 4 + 1) * 16 + c4];
            const float4 w2 = Ws[(k4 * 4 + 2) * 16 + c4];
            const float4 w3 = Ws[(k4 * 4 + 3) * 16 + c4];
            fma4(a0, x0, w0, w1, w2, w3);
            fma4(a1, x1, w0, w1, w2, w3);
            fma4(a2, x2, w0, w1, w2, w3);
            fma4(a3, x3, w0, w1, w2, w3);
        }
        if (r0 + 0 < n) ((uint2*)HSB)[((size_t)(r0 + 0) * 32 + c4 * 2) >> 1] = packbf4(a0, dinv[r0 + 0]);
        if (r0 + 1 < n) ((uint2*)HSB)[((size_t)(r0 + 1) * 32 + c4 * 2) >> 1] = packbf4(a1, dinv[r0 + 1]);
        if (r0 + 2 < n) ((uint2*)HSB)[((size_t)(r0 + 2) * 32 + c4 * 2) >> 1] = packbf4(a2, dinv[r0 + 2]);
        if (r0 + 3 < n) ((uint2*)HSB)[((size_t)(r0 + 3) * 32 + c4 * 2) >> 1] = packbf4(a3, dinv[r0 + 3]);
    }
}

// ---------------------------------------------------------------------------
// k_gg2: FUSED gather1+ReLU (phase A, lean, unroll-8, results to LDS) and
// GEMM2 (phase B, W2 in LDS, 8 fp32 accs/thread, coalesced bf16 store).
// ---------------------------------------------------------------------------
__global__ __launch_bounds__(256) void k_gg2(const int* __restrict__ rowstart,
                                             const int* __restrict__ rowcnt,
                                             const unsigned short* __restrict__ edata,
                                             const uint32_t* __restrict__ hsb1,
                                             const float* __restrict__ dinv,
                                             const float* __restrict__ b1v,
                                             const float* __restrict__ W2,
                                             uint32_t* __restrict__ hsb2) {
    __shared__ float W2s[64 * 64];            // 16KB row-major [k][c]
    __shared__ float a1s[32][68];             // 8.7KB padded
    const int tid = threadIdx.x;

    for (int f = tid; f < 1024; f += 256)
        ((float4*)W2s)[f] = ((const float4*)W2)[f];

    // ---- phase A: gather + bias + relu -> a1s ----
    const int nl = tid >> 3;
    const int lane = tid & 7;
    const int node = blockIdx.x * 32 + nl;
    if (node < N_NODES) {
        int start = rowstart[node];
        int end   = start + rowcnt[node];
        const uint4* hq = (const uint4*)hsb1;
        float a0 = 0.f, a1 = 0.f, a2 = 0.f, a3 = 0.f,
              a4 = 0.f, a5 = 0.f, a6 = 0.f, a7 = 0.f;
        int j = start;
        for (; j + 8 <= end; j += 8) {
            const int s0 = edata[j + 0];
            const int s1 = edata[j + 1];
            const int s2 = edata[j + 2];
            const int s3 = edata[j + 3];
            const int s4 = edata[j + 4];
            const int s5 = edata[j + 5];
            const int s6 = edata[j + 6];
            const int s7 = edata[j + 7];
            const uint4 v0 = hq[(size_t)s0 * 8 + lane];
            const uint4 v1 = hq[(size_t)s1 * 8 + lane];
            const uint4 v2 = hq[(size_t)s2 * 8 + lane];
            const uint4 v3 = hq[(size_t)s3 * 8 + lane];
            const uint4 v4 = hq[(size_t)s4 * 8 + lane];
            const uint4 v5 = hq[(size_t)s5 * 8 + lane];
            const uint4 v6 = hq[(size_t)s6 * 8 + lane];
            const uint4 v7 = hq[(size_t)s7 * 8 + lane];
            a0 += ((bflo(v0.x) + bflo(v1.x)) + (bflo(v2.x) + bflo(v3.x)))
                + ((bflo(v4.x) + bflo(v5.x)) + (bflo(v6.x) + bflo(v7.x)));
            a1 += ((bfhi(v0.x) + bfhi(v1.x)) + (bfhi(v2.x) + bfhi(v3.x)))
                + ((bfhi(v4.x) + bfhi(v5.x)) + (bfhi(v6.x) + bfhi(v7.x)));
            a2 += ((bflo(v0.y) + bflo(v1.y)) + (bflo(v2.y) + bflo(v3.y)))
                + ((bflo(v4.y) + bflo(v5.y)) + (bflo(v6.y) + bflo(v7.y)));
            a3 += ((bfhi(v0.y) + bfhi(v1.y)) + (bfhi(v2.y) + bfhi(v3.y)))
                + ((bfhi(v4.y) + bfhi(v5.y)) + (bfhi(v6.y) + bfhi(v7.y)));
            a4 += ((bflo(v0.z) + bflo(v1.z)) + (bflo(v2.z) + bflo(v3.z)))
                + ((bflo(v4.z) + bflo(v5.z)) + (bflo(v6.z) + bflo(v7.z)));
            a5 += ((bfhi(v0.z) + bfhi(v1.z)) + (bfhi(v2.z) + bfhi(v3.z)))
                + ((bfhi(v4.z) + bfhi(v5.z)) + (bfhi(v6.z) + bfhi(v7.z)));
            a6 += ((bflo(v0.w) + bflo(v1.w)) + (bflo(v2.w) + bflo(v3.w)))
                + ((bflo(v4.w) + bflo(v5.w)) + (bflo(v6.w) + bflo(v7.w)));
            a7 += ((bfhi(v0.w) + bfhi(v1.w)) + (bfhi(v2.w) + bfhi(v3.w)))
                + ((bfhi(v4.w) + bfhi(v5.w)) + (bfhi(v6.w) + bfhi(v7.w)));
        }
        for (; j + 4 <= end; j += 4) {
            const int s0 = edata[j + 0];
            const int s1 = edata[j + 1];
            const int s2 = edata[j + 2];
            const int s3 = edata[j + 3];
            const uint4 v0 = hq[(size_t)s0 * 8 + lane];
            const uint4 v1 = hq[(size_t)s1 * 8 + lane];
            const uint4 v2 = hq[(size_t)s2 * 8 + lane];
            const uint4 v3 = hq[(size_t)s3 * 8 + lane];
            a0 += (bflo(v0.x) + bflo(v1.x)) + (bflo(v2.x) + bflo(v3.x));
            a1 += (bfhi(v0.x) + bfhi(v1.x)) + (bfhi(v2.x) + bfhi(v3.x));
            a2 += (bflo(v0.y) + bflo(v1.y)) + (bflo(v2.y) + bflo(v3.y));
            a3 += (bfhi(v0.y) + bfhi(v1.y)) + (bfhi(v2.y) + bfhi(v3.y));
            a4 += (bflo(v0.z) + bflo(v1.z)) + (bflo(v2.z) + bflo(v3.z));
            a5 += (bfhi(v0.z) + bfhi(v1.z)) + (bfhi(v2.z) + bfhi(v3.z));
            a6 += (bflo(v0.w) + bflo(v1.w)) + (bflo(v2.w) + bflo(v3.w));
            a7 += (bfhi(v0.w) + bfhi(v1.w)) + (bfhi(v2.w) + bfhi(v3.w));
        }
        for (; j < end; ++j) {
            const int s = edata[j];
            const uint4 v = hq[(size_t)s * 8 + lane];
            a0 += bflo(v.x); a1 += bfhi(v.x);
            a2 += bflo(v.y); a3 += bfhi(v.y);
            a4 += bflo(v.z); a5 += bfhi(v.z);
            a6 += bflo(v.w); a7 += bfhi(v.w);
        }
        {
            const uint4 v = hq[(size_t)node * 8 + lane];
            a0 += bflo(v.x); a1 += bfhi(v.x);
            a2 += bflo(v.y); a3 += bfhi(v.y);
            a4 += bflo(v.z); a5 += bfhi(v.z);
            a6 += bflo(v.w); a7 += bfhi(v.w);
        }
        const float di = dinv[node];
        const float4 b0 = *reinterpret_cast<const float4*>(&b1v[lane * 8]);
        const float4 b1 = *reinterpret_cast<const float4*>(&b1v[lane * 8 + 4]);
        float4 o0, o1;
        o0.x = fmaxf(a0 * di + b0.x, 0.f);
        o0.y = fmaxf(a1 * di + b0.y, 0.f);
        o0.z = fmaxf(a2 * di + b0.z, 0.f);
        o0.w = fmaxf(a3 * di + b0.w, 0.f);
        o1.x = fmaxf(a4 * di + b1.x, 0.f);
        o1.y = fmaxf(a5 * di + b1.y, 0.f);
        o1.z = fmaxf(a6 * di + b1.z, 0.f);
        o1.w = fmaxf(a7 * di + b1.w, 0.f);
        *reinterpret_cast<float4*>(&a1s[nl][lane * 8])     = o0;
        *reinterpret_cast<float4*>(&a1s[nl][lane * 8 + 4]) = o1;
    }

    __syncthreads();

    // ---- phase B: hs2[node] = (a1s[node] @ W2) * dinv, packed bf16 ----
    const int gnode = blockIdx.x * 32 + (tid >> 3);
    if (gnode < N_NODES) {
        const int c8 = (tid & 7) * 8;
        const int nb = tid >> 3;
        float c0 = 0.f, c1 = 0.f, c2 = 0.f, c3 = 0.f,
              c4 = 0.f, c5 = 0.f, c6 = 0.f, c7 = 0.f;
#pragma unroll 8
        for (int k = 0; k < 64; ++k) {
            const float a = a1s[nb][k];
            const float4 w0 = *(const float4*)&W2s[k * 64 + c8];
            const float4 w1 = *(const float4*)&W2s[k * 64 + c8 + 4];
            c0 += a * w0.x; c1 += a * w0.y; c2 += a * w0.z; c3 += a * w0.w;
            c4 += a * w1.x; c5 += a * w1.y; c6 += a * w1.z; c7 += a * w1.w;
        }
        const float di = dinv[gnode];
        uint4 o;
        o.x = pack2bf(c0 * di, c1 * di);
        o.y = pack2bf(c2 * di, c3 * di);
        o.z = pack2bf(c4 * di, c5 * di);
        o.w = pack2bf(c6 * di, c7 * di);
        ((uint4*)hsb2)[(size_t)gnode * 8 + (tid & 7)] = o;
    }
}

// ---------------------------------------------------------------------------
// k_gather: full-row CSR gather, UNROLL-8 (layer-2 aggregate -> out).
// ---------------------------------------------------------------------------
template <bool RELU>
__global__ __launch_bounds__(256) void k_gather(const int* __restrict__ rowstart,
                                                const int* __restrict__ rowcnt,
                                                const unsigned short* __restrict__ edata,
                                                const uint32_t* __restrict__ hsb,
                                                const float* __restrict__ dinv,
                                                const float* __restrict__ bias,
                                                float* __restrict__ out) {
    int node = blockIdx.x * 32 + (threadIdx.x >> 3);
    int lane = threadIdx.x & 7;
    if (node >= N_NODES) return;

    int start = rowstart[node];
    int end   = start + rowcnt[node];

    const uint4* hq = (const uint4*)hsb;
    float a0 = 0.f, a1 = 0.f, a2 = 0.f, a3 = 0.f,
          a4 = 0.f, a5 = 0.f, a6 = 0.f, a7 = 0.f;

    int j = start;
    for (; j + 8 <= end; j += 8) {
        const int s0 = edata[j + 0];
        const int s1 = edata[j + 1];
        const int s2 = edata[j + 2];
        const int s3 = edata[j + 3];
        const int s4 = edata[j + 4];
        const int s5 = edata[j + 5];
        const int s6 = edata[j + 6];
        const int s7 = edata[j + 7];
        const uint4 v0 = hq[(size_t)s0 * 8 + lane];
        const uint4 v1 = hq[(size_t)s1 * 8 + lane];
        const uint4 v2 = hq[(size_t)s2 * 8 + lane];
        const uint4 v3 = hq[(size_t)s3 * 8 + lane];
        const uint4 v4 = hq[(size_t)s4 * 8 + lane];
        const uint4 v5 = hq[(size_t)s5 * 8 + lane];
        const uint4 v6 = hq[(size_t)s6 * 8 + lane];
        const uint4 v7 = hq[(size_t)s7 * 8 + lane];
        a0 += ((bflo(v0.x) + bflo(v1.x)) + (bflo(v2.x) + bflo(v3.x)))
            + ((bflo(v4.x) + bflo(v5.x)) + (bflo(v6.x) + bflo(v7.x)));
        a1 += ((bfhi(v0.x) + bfhi(v1.x)) + (bfhi(v2.x) + bfhi(v3.x)))
            + ((bfhi(v4.x) + bfhi(v5.x)) + (bfhi(v6.x) + bfhi(v7.x)));
        a2 += ((bflo(v0.y) + bflo(v1.y)) + (bflo(v2.y) + bflo(v3.y)))
            + ((bflo(v4.y) + bflo(v5.y)) + (bflo(v6.y) + bflo(v7.y)));
        a3 += ((bfhi(v0.y) + bfhi(v1.y)) + (bfhi(v2.y) + bfhi(v3.y)))
            + ((bfhi(v4.y) + bfhi(v5.y)) + (bfhi(v6.y) + bfhi(v7.y)));
        a4 += ((bflo(v0.z) + bflo(v1.z)) + (bflo(v2.z) + bflo(v3.z)))
            + ((bflo(v4.z) + bflo(v5.z)) + (bflo(v6.z) + bflo(v7.z)));
        a5 += ((bfhi(v0.z) + bfhi(v1.z)) + (bfhi(v2.z) + bfhi(v3.z)))
            + ((bfhi(v4.z) + bfhi(v5.z)) + (bfhi(v6.z) + bfhi(v7.z)));
        a6 += ((bflo(v0.w) + bflo(v1.w)) + (bflo(v2.w) + bflo(v3.w)))
            + ((bflo(v4.w) + bflo(v5.w)) + (bflo(v6.w) + bflo(v7.w)));
        a7 += ((bfhi(v0.w) + bfhi(v1.w)) + (bfhi(v2.w) + bfhi(v3.w)))
            + ((bfhi(v4.w) + bfhi(v5.w)) + (bfhi(v6.w) + bfhi(v7.w)));
    }
    for (; j + 4 <= end; j += 4) {
        const int s0 = edata[j + 0];
        const int s1 = edata[j + 1];
        const int s2 = edata[j + 2];
        const int s3 = edata[j + 3];
        const uint4 v0 = hq[(size_t)s0 * 8 + lane];
        const uint4 v1 = hq[(size_t)s1 * 8 + lane];
        const uint4 v2 = hq[(size_t)s2 * 8 + lane];
        const uint4 v3 = hq[(size_t)s3 * 8 + lane];
        a0 += (bflo(v0.x) + bflo(v1.x)) + (bflo(v2.x) + bflo(v3.x));
        a1 += (bfhi(v0.x) + bfhi(v1.x)) + (bfhi(v2.x) + bfhi(v3.x));
        a2 += (bflo(v0.y) + bflo(v1.y)) + (bflo(v2.y) + bflo(v3.y));
        a3 += (bfhi(v0.y) + bfhi(v1.y)) + (bfhi(v2.y) + bfhi(v3.y));
        a4 += (bflo(v0.z) + bflo(v1.z)) + (bflo(v2.z) + bflo(v3.z));
        a5 += (bfhi(v0.z) + bfhi(v1.z)) + (bfhi(v2.z) + bfhi(v3.z));
        a6 += (bflo(v0.w) + bflo(v1.w)) + (bflo(v2.w) + bflo(v3.w));
        a7 += (bfhi(v0.w) + bfhi(v1.w)) + (bfhi(v2.w) + bfhi(v3.w));
    }
    for (; j < end; ++j) {
        const int s = edata[j];
        const uint4 v = hq[(size_t)s * 8 + lane];
        a0 += bflo(v.x); a1 += bfhi(v.x);
        a2 += bflo(v.y); a3 += bfhi(v.y);
        a4 += bflo(v.z); a5 += bfhi(v.z);
        a6 += bflo(v.w); a7 += bfhi(v.w);
    }
    {
        const uint4 v = hq[(size_t)node * 8 + lane];
        a0 += bflo(v.x); a1 += bfhi(v.x);
        a2 += bflo(v.y); a3 += bfhi(v.y);
        a4 += bflo(v.z); a5 += bfhi(v.z);
        a6 += bflo(v.w); a7 += bfhi(v.w);
    }

    const float di = dinv[node];
    const float4 b0 = *reinterpret_cast<const float4*>(&bias[lane * 8]);
    const float4 b1 = *reinterpret_cast<const float4*>(&bias[lane * 8 + 4]);
    float4 o0, o1;
    o0.x = a0 * di + b0.x;  o0.y = a1 * di + b0.y;
    o0.z = a2 * di + b0.z;  o0.w = a3 * di + b0.w;
    o1.x = a4 * di + b1.x;  o1.y = a5 * di + b1.y;
    o1.z = a6 * di + b1.z;  o1.w = a7 * di + b1.w;
    if (RELU) {
        o0.x = fmaxf(o0.x, 0.f); o0.y = fmaxf(o0.y, 0.f);
        o0.z = fmaxf(o0.z, 0.f); o0.w = fmaxf(o0.w, 0.f);
        o1.x = fmaxf(o1.x, 0.f); o1.y = fmaxf(o1.y, 0.f);
        o1.z = fmaxf(o1.z, 0.f); o1.w = fmaxf(o1.w, 0.f);
    }
    float4* op = (float4*)&out[(size_t)node * 64 + lane * 8];
    op[0] = o0;
    op[1] = o1;
}

extern "C" void kernel_launch(void* const* d_in, const int* in_sizes, int n_in,
                              void* d_out, int out_size, void* d_ws, size_t ws_size,
                              hipStream_t stream) {
    const float* x  = (const float*)d_in[0];
    const int*   ei = (const int*)d_in[1];    // [2, N_EDGES] int32
    const float* W1 = (const float*)d_in[2];
    const float* b1 = (const float*)d_in[3];
    const float* W2 = (const float*)d_in[4];
    const float* b2 = (const float*)d_in[5];
    float* out = (float*)d_out;

    // Workspace carve-up (16B-aligned chunks):
    //   bucketcnt[128] | brec[NB*BCAP] | rowstart[N+4] | rowcnt[N+4] |
    //   edata ushort[NB*BCAP] | dinv[N] | hsb1[N*32 u32] | hsb2[N*32 u32]
    int*            bucketcnt = (int*)d_ws;
    int*            brec      = bucketcnt + 128;
    int*            rowstart  = brec + NB * BCAP;              // 1,003,520
    int*            rowcnt    = rowstart + (N_NODES + 4);
    unsigned short* edata     = (unsigned short*)(rowcnt + (N_NODES + 4));
    float*          dinv      = (float*)(edata + NB * BCAP);   // even count -> aligned
    uint32_t*       hsb1      = (uint32_t*)(dinv + N_NODES);   // bf16 [N][64]
    uint32_t*       hsb2      = hsb1 + (size_t)N_NODES * 32;   // bf16 [N][64]

    // --- CSR build (3 dispatches: zero cursors, fused hist+partition, CSR) ---
    k_zc<<<1, 128, 0, stream>>>(bucketcnt);
    k_part2<<<NPB, 256, 0, stream>>>(ei, bucketcnt, brec);
    k_csr2<<<NB, 256, 0, stream>>>(brec, bucketcnt, rowstart, rowcnt, dinv, edata);

    // --- layer 1 GEMM ---
    k_gemm3<IN_DIM><<<(N_NODES + 63) / 64, 256, 0, stream>>>(x, W1, dinv, hsb1, N_NODES);
    // --- fused gather1 + ReLU + GEMM2 ---
    k_gg2<<<(N_NODES + 31) / 32, 256, 0, stream>>>(rowstart, rowcnt, edata, hsb1, dinv, b1, W2, hsb2);
    // --- layer 2 aggregate ---
    k_gather<false><<<(N_NODES + 31) / 32, 256, 0, stream>>>(rowstart, rowcnt, edata, hsb2, dinv, b2, out);
}